// Round 13
// baseline (789.723 us; speedup 1.0000x reference)
//
#include <hip/hip_runtime.h>

// AttentionRNN: B=64, NUM=8, TC=64, H=128. bn=512 sequences.
// R13: 4 seqs/block, 128 blocks x 256 threads (1 wave/SIMD, 1 block/CU via
// 86KB LDS pad). Halves per-XCD weight traffic vs R12 (same 393KB/step now
// serves 4 seqs). A = full 128-dot/thread (no B phase). D = 256 threads x
// 3 cols (float3), 4 seq accumulators, 8x16-row chunks (R9 pattern, no manual
// dbuf). C: upreg[2][64], max-free softmax (validated). 5 barriers/step.

#define OFF_ATTW  0       // [128][64]
#define OFF_U     8192    // [64][64] (prologue only)
#define OFF_XMRM  12288   // [mat(2)][seq(4)][384]
#define OFF_HST   15360   // [4][128]
#define OFF_HPART 15872   // [4][64]
#define OFF_XTV   16128   // [4][128]
#define OFF_VV    16640   // [64]
#define OFF_RED   16704   // [4][2]
#define LDS_FLOATS 22016  // 86KB -> forces 1 block/CU

#define FMA3(ACC, W, S) do { (ACC).x += (W).x*(S); (ACC).y += (W).y*(S); \
                             (ACC).z += (W).z*(S); } while(0)

__global__ __launch_bounds__(256, 1)
void attn_gru_kernel(const float* __restrict__ x, const float* __restrict__ att_v,
                     const float* __restrict__ att_w, const float* __restrict__ att_u,
                     const float* __restrict__ gk, const float* __restrict__ grk,
                     const float* __restrict__ gbias, float* __restrict__ out) {
    __shared__ float lds[LDS_FLOATS];
    const int tid = threadIdx.x;
    const int bn0 = blockIdx.x * 4;

    // ---- stage att_w, U, v; zero h[4][128]
    for (int i = tid; i < 8192; i += 256) lds[OFF_ATTW + i] = att_w[i];
    for (int i = tid; i < 4096; i += 256) lds[OFF_U + i] = att_u[i];
    if (tid < 64) lds[OFF_VV + tid] = att_v[tid];
    lds[OFF_HST + tid] = 0.0f;
    lds[OFF_HST + 256 + tid] = 0.0f;
    __syncthreads();

    // ---- thread mappings
    const int c2  = tid >> 7;     // C/E: handles seqs {c2, c2+2}
    const int chh = tid & 127;    // feature
    const int w_  = tid >> 6;     // wave id
    const int asq = w_;           // A: seq = wave
    const int as_ = tid & 63;     // A: s index
    // D: 256 threads x 3 cols. tid<128 -> gk (input XTV), else grk (input HST)
    const int dmat = (tid >= 128) ? 1 : 0;
    const int dc   = 3 * (tid & 127);          // col base within matrix
    const float* Wm = (dmat ? grk : gk) + dc;
    const int din   = dmat ? OFF_HST : OFF_XTV;
    const float3 b3 = *(const float3*)(gbias + dmat * 384 + dc);

    // ---- prologue: uproj for both owned seqs (2x64 regs, static-indexed)
    float up0[64], up1[64];
    #pragma unroll
    for (int s2 = 0; s2 < 64; ++s2) { up0[s2] = 0.0f; up1[s2] = 0.0f; }
    {
        const float* xb0 = x + (size_t)(bn0 + c2) * 8192 + chh;
        const float* xb1 = x + (size_t)(bn0 + c2 + 2) * 8192 + chh;
        for (int t = 0; t < 64; ++t) {
            float xv0 = xb0[t * 128];
            float xv1 = xb1[t * 128];
            const float* Ur = lds + OFF_U + t * 64;
            #pragma unroll
            for (int s2 = 0; s2 < 64; ++s2) {
                float u = Ur[s2];
                up0[s2] += xv0 * u;
                up1[s2] += xv1 * u;
            }
        }
    }
    float sv = 0.0f;
    #pragma unroll
    for (int s2 = 0; s2 < 64; ++s2) sv += lds[OFF_VV + s2];

    const float* xc0 = x + (size_t)(bn0 + c2) * 8192 + chh;
    const float* xc1 = x + (size_t)(bn0 + c2 + 2) * 8192 + chh;

    __syncthreads();

    for (int t = 0; t < 64; ++t) {
        float xv0 = xc0[t * 128];   // prefetch both seqs' x (L3-hot)
        float xv1 = xc1[t * 128];

        // ---- A: h_part[asq][as_] = full 128-dot (no partials, no B phase)
        {
            float pa = 0.0f;
            const float4* hb4 = (const float4*)(lds + OFF_HST + asq * 128);
            const float* wgl = lds + OFF_ATTW + as_;      // lane-consecutive
            #pragma unroll
            for (int k4 = 0; k4 < 32; ++k4) {
                float4 hv = hb4[k4];
                pa += hv.x * wgl[(k4*4+0)*64] + hv.y * wgl[(k4*4+1)*64]
                    + hv.z * wgl[(k4*4+2)*64] + hv.w * wgl[(k4*4+3)*64];
            }
            lds[OFF_HPART + asq * 64 + as_] = pa;
        }
        __syncthreads();

        // ---- C: e for seqs c2 and c2+2 at feature chh; max-free softmax
        float den0 = 0.0f, den1 = 0.0f;
        {
            const float* hp0 = lds + OFF_HPART + c2 * 64;
            const float* hp1 = lds + OFF_HPART + (c2 + 2) * 64;
            #pragma unroll
            for (int s2 = 0; s2 < 64; ++s2) {
                float v = lds[OFF_VV + s2];
                den0 += v * __fdividef(1.0f, __expf(2.0f * (hp0[s2] + up0[s2])) + 1.0f);
                den1 += v * __fdividef(1.0f, __expf(2.0f * (hp1[s2] + up1[s2])) + 1.0f);
            }
        }
        float e0 = sv - 2.0f * den0;
        float e1 = sv - 2.0f * den1;
        float p0 = __expf(e0);              // |e| <= sum|v| ~ 5: fp32-safe
        float p1 = __expf(e1);
        float ws0 = p0, ws1 = p1;
        #pragma unroll
        for (int off = 1; off <= 32; off <<= 1) {
            ws0 += __shfl_xor(ws0, off);
            ws1 += __shfl_xor(ws1, off);
        }
        if ((tid & 63) == 0) {
            lds[OFF_RED + w_ * 2 + 0] = ws0;
            lds[OFF_RED + w_ * 2 + 1] = ws1;
        }
        __syncthreads();
        float d0 = lds[OFF_RED + (2 * c2) * 2 + 0] + lds[OFF_RED + (2 * c2 + 1) * 2 + 0];
        float d1 = lds[OFF_RED + (2 * c2) * 2 + 1] + lds[OFF_RED + (2 * c2 + 1) * 2 + 1];
        lds[OFF_XTV + c2 * 128 + chh]       = __fdividef(p0, d0) * xv0;
        lds[OFF_XTV + (c2 + 2) * 128 + chh] = __fdividef(p1, d1) * xv1;
        __syncthreads();

        // ---- D: 8 chunks x 16 rows, float3 col-triple per thread, 4 seq accs
        {
            float3 acc0 = {0.f, 0.f, 0.f};
            float3 acc1 = {0.f, 0.f, 0.f};
            float3 acc2 = {0.f, 0.f, 0.f};
            float3 acc3 = {0.f, 0.f, 0.f};
            #pragma unroll 1
            for (int c = 0; c < 8; ++c) {
                float3 w[16];
                #pragma unroll
                for (int r = 0; r < 16; ++r)
                    w[r] = *(const float3*)(Wm + (size_t)(c * 16 + r) * 384);
                const float* ib = lds + din + c * 16;
                #pragma unroll
                for (int r4 = 0; r4 < 4; ++r4) {
                    float4 i0 = *(const float4*)(ib + 0 * 128 + r4 * 4);
                    float4 i1 = *(const float4*)(ib + 1 * 128 + r4 * 4);
                    float4 i2 = *(const float4*)(ib + 2 * 128 + r4 * 4);
                    float4 i3 = *(const float4*)(ib + 3 * 128 + r4 * 4);
                    FMA3(acc0, w[r4*4+0], i0.x); FMA3(acc1, w[r4*4+0], i1.x);
                    FMA3(acc2, w[r4*4+0], i2.x); FMA3(acc3, w[r4*4+0], i3.x);
                    FMA3(acc0, w[r4*4+1], i0.y); FMA3(acc1, w[r4*4+1], i1.y);
                    FMA3(acc2, w[r4*4+1], i2.y); FMA3(acc3, w[r4*4+1], i3.y);
                    FMA3(acc0, w[r4*4+2], i0.z); FMA3(acc1, w[r4*4+2], i1.z);
                    FMA3(acc2, w[r4*4+2], i2.z); FMA3(acc3, w[r4*4+2], i3.z);
                    FMA3(acc0, w[r4*4+3], i0.w); FMA3(acc1, w[r4*4+3], i1.w);
                    FMA3(acc2, w[r4*4+3], i2.w); FMA3(acc3, w[r4*4+3], i3.w);
                }
            }
            float* xmb = lds + OFF_XMRM + dmat * 4 * 384 + dc;
            *(float3*)(xmb + 0 * 384) = make_float3(acc0.x + b3.x, acc0.y + b3.y, acc0.z + b3.z);
            *(float3*)(xmb + 1 * 384) = make_float3(acc1.x + b3.x, acc1.y + b3.y, acc1.z + b3.z);
            *(float3*)(xmb + 2 * 384) = make_float3(acc2.x + b3.x, acc2.y + b3.y, acc2.z + b3.z);
            *(float3*)(xmb + 3 * 384) = make_float3(acc3.x + b3.x, acc3.y + b3.y, acc3.z + b3.z);
        }
        __syncthreads();

        // ---- E: gates + h update for seqs c2 and c2+2 at feature chh
        #pragma unroll
        for (int j = 0; j < 2; ++j) {
            const int sq = c2 + 2 * j;
            const float* xm = lds + OFF_XMRM + sq * 384;
            const float* rm = lds + OFF_XMRM + (4 + sq) * 384;
            float xz = xm[chh], xr = xm[128 + chh], xh_ = xm[256 + chh];
            float rz = rm[chh], rr = rm[128 + chh], rh = rm[256 + chh];
            float z = __fdividef(1.0f, 1.0f + __expf(-(xz + rz)));
            float r = __fdividef(1.0f, 1.0f + __expf(-(xr + rr)));
            float hc = xh_ + r * rh;
            hc = hc > 0.0f ? hc : 0.0f;
            float hold = lds[OFF_HST + sq * 128 + chh];
            lds[OFF_HST + sq * 128 + chh] = z * hold + (1.0f - z) * hc;
        }
        __syncthreads();
    }

    out[(size_t)(bn0 + c2) * 128 + chh]     = lds[OFF_HST + c2 * 128 + chh];
    out[(size_t)(bn0 + c2 + 2) * 128 + chh] = lds[OFF_HST + (c2 + 2) * 128 + chh];
}

extern "C" void kernel_launch(void* const* d_in, const int* in_sizes, int n_in,
                              void* d_out, int out_size, void* d_ws, size_t ws_size,
                              hipStream_t stream) {
    (void)in_sizes; (void)n_in; (void)out_size; (void)d_ws; (void)ws_size;
    const float* x      = (const float*)d_in[0];
    const float* att_v  = (const float*)d_in[1];
    const float* att_w  = (const float*)d_in[2];
    const float* att_u  = (const float*)d_in[3];
    const float* gk     = (const float*)d_in[4];
    const float* grk    = (const float*)d_in[5];
    const float* gbias  = (const float*)d_in[6];
    float* out = (float*)d_out;
    hipLaunchKernelGGL(attn_gru_kernel, dim3(128), dim3(256), 0, stream,
                       x, att_v, att_w, att_u, gk, grk, gbias, out);
}

// Round 14
// 545.155 us; speedup vs baseline: 1.4486x; 1.4486x over previous
//
#include <hip/hip_runtime.h>

// AttentionRNN: B=64, NUM=8, TC=64, H=128. bn=512 sequences.
// R14 = R12/R9 base (256 thr, 2 seqs, launch_bounds(256,1)) + LDS-resident
// weight rows 0..47 of gk+grk (144KB; LDS ~155KB, 1 block/CU) + early-issued
// first streamed chunk (lands under phase C) + 4 streamed chunks interleaved
// with resident-FMA blocks. A/B = R9 (wreg in regs). C/E = R12 (validated).

#define OFF_WL    0        // [2][48][384] resident rows; U aliased here in prologue
#define OFF_XMRM  36864    // [mat][seq][384]
#define OFF_HST   38400    // [2][128]
#define OFF_HPP   38656    // [2][4][64]
#define OFF_HPART 39168    // [2][64]
#define OFF_XTV   39296    // [2][128]
#define OFF_VV    39552    // [64]
#define OFF_RED   39616    // [16]
#define LDS_FLOATS 39632   // ~154.8 KB

#define FMA4(ACC, W, S) do { (ACC).x += (W).x*(S); (ACC).y += (W).y*(S); \
                             (ACC).z += (W).z*(S); (ACC).w += (W).w*(S); } while(0)

// load 16 float4 weight rows RB..RB+15 from global
#define LOADW(BUF, RB) do { \
    _Pragma("unroll") \
    for (int r_ = 0; r_ < 16; ++r_) \
        BUF[r_] = *(const float4*)(Wm + (size_t)((RB) + r_) * 384); \
} while (0)

// FMA 16-row chunk BUF (rows RB..RB+15) against both seqs' inputs
#define FMACH(BUF, RB) do { \
    const float* i0_ = lds + ivoff + (RB); \
    float4 iA0 = *(const float4*)(i0_); \
    float4 iA1 = *(const float4*)(i0_ + 4); \
    float4 iA2 = *(const float4*)(i0_ + 8); \
    float4 iA3 = *(const float4*)(i0_ + 12); \
    float4 iB0 = *(const float4*)(i0_ + 128); \
    float4 iB1 = *(const float4*)(i0_ + 132); \
    float4 iB2 = *(const float4*)(i0_ + 136); \
    float4 iB3 = *(const float4*)(i0_ + 140); \
    FMA4(a0, BUF[0],  iA0.x); FMA4(a1, BUF[0],  iB0.x); \
    FMA4(a0, BUF[1],  iA0.y); FMA4(a1, BUF[1],  iB0.y); \
    FMA4(a0, BUF[2],  iA0.z); FMA4(a1, BUF[2],  iB0.z); \
    FMA4(a0, BUF[3],  iA0.w); FMA4(a1, BUF[3],  iB0.w); \
    FMA4(a0, BUF[4],  iA1.x); FMA4(a1, BUF[4],  iB1.x); \
    FMA4(a0, BUF[5],  iA1.y); FMA4(a1, BUF[5],  iB1.y); \
    FMA4(a0, BUF[6],  iA1.z); FMA4(a1, BUF[6],  iB1.z); \
    FMA4(a0, BUF[7],  iA1.w); FMA4(a1, BUF[7],  iB1.w); \
    FMA4(a0, BUF[8],  iA2.x); FMA4(a1, BUF[8],  iB2.x); \
    FMA4(a0, BUF[9],  iA2.y); FMA4(a1, BUF[9],  iB2.y); \
    FMA4(a0, BUF[10], iA2.z); FMA4(a1, BUF[10], iB2.z); \
    FMA4(a0, BUF[11], iA2.w); FMA4(a1, BUF[11], iB2.w); \
    FMA4(a0, BUF[12], iA3.x); FMA4(a1, BUF[12], iB3.x); \
    FMA4(a0, BUF[13], iA3.y); FMA4(a1, BUF[13], iB3.y); \
    FMA4(a0, BUF[14], iA3.z); FMA4(a1, BUF[14], iB3.z); \
    FMA4(a0, BUF[15], iA3.w); FMA4(a1, BUF[15], iB3.w); \
} while (0)

// resident-row FMAs: rows R0..R1-1 from LDS (separate pipe from L2 stream)
#define RESFMA(R0, R1) do { \
    _Pragma("unroll") \
    for (int r_ = (R0); r_ < (R1); ++r_) { \
        float4 wr_ = *(const float4*)(lds + wlbase + r_ * 384); \
        float iw0_ = lds[ivoff + r_]; \
        float iw1_ = lds[ivoff + 128 + r_]; \
        FMA4(a0, wr_, iw0_); FMA4(a1, wr_, iw1_); \
    } \
} while (0)

__global__ __launch_bounds__(256, 1)
void attn_gru_kernel(const float* __restrict__ x, const float* __restrict__ att_v,
                     const float* __restrict__ att_w, const float* __restrict__ att_u,
                     const float* __restrict__ gk, const float* __restrict__ grk,
                     const float* __restrict__ gbias, float* __restrict__ out) {
    __shared__ float lds[LDS_FLOATS];
    const int tid = threadIdx.x;
    const int bn0 = blockIdx.x * 2;

    // ---- prologue 1: U (aliased into WLDS), v, h=0
    for (int i = tid; i < 4096; i += 256) lds[OFF_WL + i] = att_u[i];
    if (tid < 64) lds[OFF_VV + tid] = att_v[tid];
    lds[OFF_HST + tid] = 0.0f;
    __syncthreads();

    const int seq = tid >> 7;   // 0/1
    const int hh  = tid & 127;
    const int s_  = tid & 63;
    const int hg  = tid >> 6;   // wave id

    // uproj[seq][hh][0..63] in registers (R9-validated)
    float upreg[64];
    #pragma unroll
    for (int s2 = 0; s2 < 64; ++s2) upreg[s2] = 0.0f;
    {
        const float* xb = x + (size_t)(bn0 + seq) * 8192 + hh;
        for (int t = 0; t < 64; ++t) {
            float xv = xb[t * 128];
            const float* Ur = lds + OFF_WL + t * 64;
            #pragma unroll
            for (int s2 = 0; s2 < 64; ++s2) upreg[s2] += xv * Ur[s2];
        }
    }
    // att_w fragment in registers (R9-validated A)
    float wreg[32];
    #pragma unroll
    for (int k = 0; k < 32; ++k) wreg[k] = att_w[(hg * 32 + k) * 64 + s_];

    __syncthreads();   // U reads done -> safe to overwrite with resident weights

    // ---- prologue 2: resident weight rows 0..47 of both matrices into WLDS
    for (int i = tid; i < 36864; i += 256) {
        int mat = i / 18432;
        int rc  = i - mat * 18432;               // r*384 + c, r < 48
        lds[OFF_WL + i] = (mat ? grk : gk)[rc];
    }

    // phase-D per-thread constants (R12-validated mapping)
    const int col4 = tid * 4;                 // 0..764 for tid<192
    const int dmat = (col4 >= 384) ? 1 : 0;
    const int dj   = col4 - dmat * 384;
    const float* Wm = (dmat ? grk : gk) + dj;
    const int ivoff  = dmat ? OFF_HST : OFF_XTV;
    const int wlbase = OFF_WL + dmat * 18432 + dj;
    float4 dbias = make_float4(0.f, 0.f, 0.f, 0.f);
    if (tid < 192) dbias = *(const float4*)(gbias + dmat * 384 + dj);

    const float* xcol = x + (size_t)(bn0 + seq) * 8192 + hh;

    __syncthreads();

    for (int t = 0; t < 64; ++t) {
        float xv = xcol[t * 128];   // prefetch (L3-hot), used in softmax phase

        // ---- A: h_part partials (R9-validated)
        {
            float p0 = 0.f, p1 = 0.f;
            #pragma unroll
            for (int k = 0; k < 32; ++k) {
                float w = wreg[k];
                p0 += lds[OFF_HST + hg * 32 + k] * w;
                p1 += lds[OFF_HST + 128 + hg * 32 + k] * w;
            }
            lds[OFF_HPP + (0 * 4 + hg) * 64 + s_] = p0;
            lds[OFF_HPP + (1 * 4 + hg) * 64 + s_] = p1;
        }
        __syncthreads();

        // ---- B: reduce 4 row-group partials (R9-validated)
        if (tid < 128) {
            int sq = tid >> 6, ss = tid & 63;
            lds[OFF_HPART + sq * 64 + ss] =
                  lds[OFF_HPP + (sq * 4 + 0) * 64 + ss]
                + lds[OFF_HPP + (sq * 4 + 1) * 64 + ss]
                + lds[OFF_HPP + (sq * 4 + 2) * 64 + ss]
                + lds[OFF_HPP + (sq * 4 + 3) * 64 + ss];
        }
        __syncthreads();

        // early-issue first streamed chunk (rows 48..63): lands under C
        float4 wpre[16];
        if (tid < 192) LOADW(wpre, 48);

        // ---- C: e = sum_s tanh(hp+up)*v; max-free softmax (R12-validated)
        float e = 0.f;
        {
            const float* hp = lds + OFF_HPART + seq * 64;
            #pragma unroll
            for (int s2 = 0; s2 < 64; ++s2) {
                float arg = hp[s2] + upreg[s2];
                float u2 = __expf(2.0f * arg);
                float th = 1.0f - __fdividef(2.0f, u2 + 1.0f);
                e += th * lds[OFF_VV + s2];
            }
        }
        float p = __expf(e);                 // |e| <= sum|v| ~ 5: fp32-safe
        float sm = p;
        #pragma unroll
        for (int off = 32; off >= 1; off >>= 1) sm += __shfl_xor(sm, off, 64);
        if ((tid & 63) == 0) lds[OFF_RED + 8 + hg] = sm;
        __syncthreads();
        float denom = lds[OFF_RED + 8 + seq * 2] + lds[OFF_RED + 8 + seq * 2 + 1];
        float a = __fdividef(p, denom);
        lds[OFF_XTV + seq * 128 + hh] = a * xv;
        __syncthreads();

        // ---- D: streamed rows 48..127 (5 chunks) + resident rows 0..47 (LDS)
        if (tid < 192) {
            float4 a0 = make_float4(0.f, 0.f, 0.f, 0.f);
            float4 a1 = make_float4(0.f, 0.f, 0.f, 0.f);
            FMACH(wpre, 48);                       // data landed during C
            {
                float4 wa[16];
                LOADW(wa, 64);  RESFMA(0, 12);  FMACH(wa, 64);
                LOADW(wa, 80);  RESFMA(12, 24); FMACH(wa, 80);
                LOADW(wa, 96);  RESFMA(24, 36); FMACH(wa, 96);
                LOADW(wa, 112); RESFMA(36, 48); FMACH(wa, 112);
            }
            *(float4*)(lds + OFF_XMRM + (dmat * 2 + 0) * 384 + dj) =
                make_float4(a0.x + dbias.x, a0.y + dbias.y, a0.z + dbias.z, a0.w + dbias.w);
            *(float4*)(lds + OFF_XMRM + (dmat * 2 + 1) * 384 + dj) =
                make_float4(a1.x + dbias.x, a1.y + dbias.y, a1.z + dbias.z, a1.w + dbias.w);
        }
        __syncthreads();

        // ---- E: gates (R12-validated)
        {
            const float* xm = lds + OFF_XMRM + (0 * 2 + seq) * 384;
            const float* rm = lds + OFF_XMRM + (1 * 2 + seq) * 384;
            float xz = xm[hh], xr = xm[128 + hh], xh = xm[256 + hh];
            float rz = rm[hh], rr = rm[128 + hh], rh = rm[256 + hh];
            float z = __fdividef(1.0f, 1.0f + __expf(-(xz + rz)));
            float r = __fdividef(1.0f, 1.0f + __expf(-(xr + rr)));
            float hc = xh + r * rh;
            hc = hc > 0.f ? hc : 0.f;
            float hold = lds[OFF_HST + seq * 128 + hh];
            lds[OFF_HST + seq * 128 + hh] = z * hold + (1.0f - z) * hc;
        }
        __syncthreads();
    }

    out[(size_t)(bn0 + seq) * 128 + hh] = lds[OFF_HST + seq * 128 + hh];
}

extern "C" void kernel_launch(void* const* d_in, const int* in_sizes, int n_in,
                              void* d_out, int out_size, void* d_ws, size_t ws_size,
                              hipStream_t stream) {
    (void)in_sizes; (void)n_in; (void)out_size; (void)d_ws; (void)ws_size;
    const float* x      = (const float*)d_in[0];
    const float* att_v  = (const float*)d_in[1];
    const float* att_w  = (const float*)d_in[2];
    const float* att_u  = (const float*)d_in[3];
    const float* gk     = (const float*)d_in[4];
    const float* grk    = (const float*)d_in[5];
    const float* gbias  = (const float*)d_in[6];
    float* out = (float*)d_out;
    hipLaunchKernelGGL(attn_gru_kernel, dim3(256), dim3(256), 0, stream,
                       x, att_v, att_w, att_u, gk, grk, gbias, out);
}